// Round 1
// baseline (192.452 us; speedup 1.0000x reference)
//
#include <hip/hip_runtime.h>
#include <hip/hip_bf16.h>
#include <stdint.h>

#define BATCH 2
#define SEQ   2048
#define DIM   1024
#define NH    16
#define HD    64
#define MVAL  (-10000.0f)

typedef __attribute__((ext_vector_type(8))) short bf16x8;
typedef __attribute__((ext_vector_type(4))) float f32x4;
typedef unsigned short u16;

static __device__ __forceinline__ u16 f2bf(float f) {
  union { float f; uint32_t u; } c; c.f = f;
  uint32_t x = c.u;
  return (u16)((x + 0x7fffu + ((x >> 16) & 1u)) >> 16);  // RNE
}

// swizzled byte offset within LDS tiles of 128B rows (8 x 16B chunks)
static __device__ __forceinline__ int swz128(int row, int chunk) {
  return row * 128 + (((chunk ^ (row & 7)) & 7) << 4);
}

// ---------------- fp32 -> bf16 convert (vectorized) ----------------
__global__ void cvt_kernel(const float* __restrict__ in, u16* __restrict__ out, int n4) {
  int i = blockIdx.x * blockDim.x + threadIdx.x;
  if (i < n4) {
    float4 v = reinterpret_cast<const float4*>(in)[i];
    uint32_t p0 = (uint32_t)f2bf(v.x) | ((uint32_t)f2bf(v.y) << 16);
    uint32_t p1 = (uint32_t)f2bf(v.z) | ((uint32_t)f2bf(v.w) << 16);
    reinterpret_cast<uint2*>(out)[i] = make_uint2(p0, p1);
  }
}

// -------- fp32 [R][C] -> bf16 [C][R] transpose via LDS tile --------
__global__ void transpose_cvt_kernel(const float* __restrict__ in, u16* __restrict__ out,
                                     int R, int C) {
  __shared__ float tile[32][33];
  int c0 = blockIdx.x * 32, r0 = blockIdx.y * 32;
  int tx = threadIdx.x, ty = threadIdx.y;
#pragma unroll
  for (int i = 0; i < 32; i += 8)
    tile[ty + i][tx] = in[(size_t)(r0 + ty + i) * C + c0 + tx];
  __syncthreads();
#pragma unroll
  for (int i = 0; i < 32; i += 8)
    out[(size_t)(c0 + ty + i) * R + r0 + tx] = f2bf(tile[tx][ty + i]);
}

// ---------------- bf16 GEMM: C = A[M,K] * Bt[N,K]^T + bias ----------------
// EPI==0: scatter to Q/K head-split [bh][s][d] and V transposed [bh][d][s] (bf16)
// EPI==1: plain fp32 [M][N] output
template <int EPI>
__global__ __launch_bounds__(256, 2) void gemm_bt_kernel(
    const u16* __restrict__ A, const u16* __restrict__ Bt,
    const float* __restrict__ bias, float* __restrict__ Cout,
    u16* __restrict__ Qo, u16* __restrict__ Ko, u16* __restrict__ Vto,
    int M, int N, int K) {
  __shared__ __align__(16) char lds[32768];
  char* As = lds;            // 128 rows x 64 bf16 (128B rows), swizzled
  char* Bs = lds + 16384;
  int tid = threadIdx.x;
  int lane = tid & 63;
  int w = tid >> 6, wr = w >> 1, wc = w & 1;
  int m0 = blockIdx.y * 128, n0 = blockIdx.x * 128;
  int srow = tid >> 3, sch = tid & 7;

  f32x4 acc[4][4] = {};

  for (int k0 = 0; k0 < K; k0 += 64) {
    __syncthreads();
#pragma unroll
    for (int i = 0; i < 4; i++) {
      int r = srow + i * 32;
      uint4 va = *reinterpret_cast<const uint4*>(A + (size_t)(m0 + r) * K + k0 + sch * 8);
      *reinterpret_cast<uint4*>(As + swz128(r, sch)) = va;
      uint4 vb = *reinterpret_cast<const uint4*>(Bt + (size_t)(n0 + r) * K + k0 + sch * 8);
      *reinterpret_cast<uint4*>(Bs + swz128(r, sch)) = vb;
    }
    __syncthreads();
#pragma unroll
    for (int ks = 0; ks < 2; ks++) {
      int ch = ks * 4 + (lane >> 4);
      bf16x8 af[4], bfv[4];
#pragma unroll
      for (int mi = 0; mi < 4; mi++)
        af[mi] = *reinterpret_cast<const bf16x8*>(As + swz128(wr * 64 + mi * 16 + (lane & 15), ch));
#pragma unroll
      for (int nj = 0; nj < 4; nj++)
        bfv[nj] = *reinterpret_cast<const bf16x8*>(Bs + swz128(wc * 64 + nj * 16 + (lane & 15), ch));
#pragma unroll
      for (int mi = 0; mi < 4; mi++)
#pragma unroll
        for (int nj = 0; nj < 4; nj++)
          acc[mi][nj] = __builtin_amdgcn_mfma_f32_16x16x32_bf16(af[mi], bfv[nj], acc[mi][nj], 0, 0, 0);
    }
  }

#pragma unroll
  for (int nj = 0; nj < 4; nj++) {
    int n = n0 + wc * 64 + nj * 16 + (lane & 15);
    float bv = bias[n];
#pragma unroll
    for (int mi = 0; mi < 4; mi++) {
#pragma unroll
      for (int r = 0; r < 4; r++) {
        int m = m0 + wr * 64 + mi * 16 + (lane >> 4) * 4 + r;
        float v = acc[mi][nj][r] + bv;
        if (EPI == 1) {
          Cout[(size_t)m * N + n] = v;
        } else {
          int b = m >> 11, s = m & 2047;
          int sec = n >> 10, c = n & 1023, h = c >> 6, d = c & 63;
          u16 xb = f2bf(v);
          size_t bh = (size_t)(b * NH + h);
          if (sec == 0)      Qo[(bh * SEQ + s) * HD + d] = xb;
          else if (sec == 1) Ko[(bh * SEQ + s) * HD + d] = xb;
          else               Vto[(bh * HD + d) * SEQ + s] = xb;
        }
      }
    }
  }
}

// ---------------- causal flash attention ----------------
// grid: (SEQ/128, BATCH*NH); block: 256 (4 waves x 32 q-rows)
__global__ __launch_bounds__(256, 2) void attn_kernel(
    const u16* __restrict__ Q, const u16* __restrict__ K,
    const u16* __restrict__ Vt, u16* __restrict__ O) {
  __shared__ __align__(16) char lds[32768];
  char* Klds = lds;           // 64 kv-rows x 64 d (bf16), swizzled
  char* Vlds = lds + 8192;    // 64 d-rows x 64 kv (bf16), swizzled
  char* Plds = lds + 16384;   // 4 waves x (32 q x 64 kv bf16)
  int tid = threadIdx.x, lane = tid & 63, w = tid >> 6;
  int bh = blockIdx.y;
  int qt = blockIdx.x;
  const u16* Qh = Q + (size_t)bh * SEQ * HD;
  const u16* Kh = K + (size_t)bh * SEQ * HD;
  const u16* Vh = Vt + (size_t)bh * HD * SEQ;
  char* Pw = Plds + w * 4096;
  int qbase = qt * 128 + w * 32;

  // Q fragments held in registers: [mi][ks]
  bf16x8 qf[2][2];
#pragma unroll
  for (int mi = 0; mi < 2; mi++)
#pragma unroll
    for (int ks = 0; ks < 2; ks++)
      qf[mi][ks] = *reinterpret_cast<const bf16x8*>(
          Qh + (size_t)(qbase + mi * 16 + (lane & 15)) * HD + ks * 32 + (lane >> 4) * 8);

  float mrun[2][4], lrun[2][4];
  f32x4 oacc[2][4] = {};
#pragma unroll
  for (int mi = 0; mi < 2; mi++)
#pragma unroll
    for (int r = 0; r < 4; r++) { mrun[mi][r] = -1e30f; lrun[mi][r] = 0.0f; }

  int nkt = (qt + 1) * 2;  // 64-wide kv tiles covering [0, qt*128+128)
  int srow = tid >> 3, sch = tid & 7;

  for (int kt = 0; kt < nkt; kt++) {
    __syncthreads();
    // stage K tile [64][64] and V^T tile [64][64]
#pragma unroll
    for (int i = 0; i < 2; i++) {
      int r = srow + i * 32;
      uint4 kv = *reinterpret_cast<const uint4*>(Kh + (size_t)(kt * 64 + r) * HD + sch * 8);
      *reinterpret_cast<uint4*>(Klds + swz128(r, sch)) = kv;
      uint4 vv = *reinterpret_cast<const uint4*>(Vh + (size_t)r * SEQ + kt * 64 + sch * 8);
      *reinterpret_cast<uint4*>(Vlds + swz128(r, sch)) = vv;
    }
    __syncthreads();

    // S = Q K^T
    f32x4 s[2][4] = {};
#pragma unroll
    for (int ks = 0; ks < 2; ks++) {
      int ch = ks * 4 + (lane >> 4);
#pragma unroll
      for (int nj = 0; nj < 4; nj++) {
        bf16x8 kf = *reinterpret_cast<const bf16x8*>(Klds + swz128(nj * 16 + (lane & 15), ch));
#pragma unroll
        for (int mi = 0; mi < 2; mi++)
          s[mi][nj] = __builtin_amdgcn_mfma_f32_16x16x32_bf16(qf[mi][ks], kf, s[mi][nj], 0, 0, 0);
      }
    }

    // scale + causal mask + tile row-max
    float mt[2][4];
#pragma unroll
    for (int mi = 0; mi < 2; mi++)
#pragma unroll
      for (int r = 0; r < 4; r++) mt[mi][r] = -1e30f;
#pragma unroll
    for (int mi = 0; mi < 2; mi++)
#pragma unroll
      for (int nj = 0; nj < 4; nj++)
#pragma unroll
        for (int r = 0; r < 4; r++) {
          int qg = qbase + mi * 16 + (lane >> 4) * 4 + r;
          int kg = kt * 64 + nj * 16 + (lane & 15);
          float v = (kg <= qg) ? s[mi][nj][r] * 0.125f : MVAL;
          s[mi][nj][r] = v;
          mt[mi][r] = fmaxf(mt[mi][r], v);
        }
#pragma unroll
    for (int mi = 0; mi < 2; mi++)
#pragma unroll
      for (int r = 0; r < 4; r++) {
        float v = mt[mi][r];
        v = fmaxf(v, __shfl_xor(v, 1));
        v = fmaxf(v, __shfl_xor(v, 2));
        v = fmaxf(v, __shfl_xor(v, 4));
        v = fmaxf(v, __shfl_xor(v, 8));
        mt[mi][r] = v;
      }

    // online-softmax update
    float alpha[2][4];
#pragma unroll
    for (int mi = 0; mi < 2; mi++)
#pragma unroll
      for (int r = 0; r < 4; r++) {
        float mnew = fmaxf(mrun[mi][r], mt[mi][r]);
        alpha[mi][r] = __expf(mrun[mi][r] - mnew);
        mrun[mi][r] = mnew;
#pragma unroll
        for (int nd = 0; nd < 4; nd++) oacc[mi][nd][r] *= alpha[mi][r];
      }

    // P = exp(S - m), write bf16 P to per-wave LDS, accumulate row sums
    float rs[2][4] = {};
#pragma unroll
    for (int mi = 0; mi < 2; mi++)
#pragma unroll
      for (int nj = 0; nj < 4; nj++)
#pragma unroll
        for (int r = 0; r < 4; r++) {
          float p = __expf(s[mi][nj][r] - mrun[mi][r]);
          rs[mi][r] += p;
          int row = mi * 16 + (lane >> 4) * 4 + r;
          int col = nj * 16 + (lane & 15);
          *reinterpret_cast<u16*>(Pw + row * 128 + ((((col >> 3) ^ (row & 7)) & 7) << 4) +
                                  (col & 7) * 2) = f2bf(p);
        }
#pragma unroll
    for (int mi = 0; mi < 2; mi++)
#pragma unroll
      for (int r = 0; r < 4; r++) {
        float v = rs[mi][r];
        v += __shfl_xor(v, 1);
        v += __shfl_xor(v, 2);
        v += __shfl_xor(v, 4);
        v += __shfl_xor(v, 8);
        lrun[mi][r] = lrun[mi][r] * alpha[mi][r] + v;
      }

    asm volatile("s_waitcnt lgkmcnt(0)" ::: "memory");
    __builtin_amdgcn_sched_barrier(0);

    // O += P V
#pragma unroll
    for (int ks = 0; ks < 2; ks++) {
      int ch = ks * 4 + (lane >> 4);
      bf16x8 pf[2];
#pragma unroll
      for (int mi = 0; mi < 2; mi++)
        pf[mi] = *reinterpret_cast<const bf16x8*>(Pw + swz128(mi * 16 + (lane & 15), ch));
#pragma unroll
      for (int nd = 0; nd < 4; nd++) {
        bf16x8 vf = *reinterpret_cast<const bf16x8*>(Vlds + swz128(nd * 16 + (lane & 15), ch));
#pragma unroll
        for (int mi = 0; mi < 2; mi++)
          oacc[mi][nd] = __builtin_amdgcn_mfma_f32_16x16x32_bf16(pf[mi], vf, oacc[mi][nd], 0, 0, 0);
      }
    }
  }

  // write O merged-heads [B][S][D] bf16
  int b = bh >> 4, h = bh & 15;
#pragma unroll
  for (int mi = 0; mi < 2; mi++)
#pragma unroll
    for (int nd = 0; nd < 4; nd++)
#pragma unroll
      for (int r = 0; r < 4; r++) {
        int qrow = qbase + mi * 16 + (lane >> 4) * 4 + r;
        int d = nd * 16 + (lane & 15);
        float v = oacc[mi][nd][r] / lrun[mi][r];
        O[((size_t)b * SEQ + qrow) * DIM + h * HD + d] = f2bf(v);
      }
}

extern "C" void kernel_launch(void* const* d_in, const int* in_sizes, int n_in,
                              void* d_out, int out_size, void* d_ws, size_t ws_size,
                              hipStream_t stream) {
  const float* x     = (const float*)d_in[0];
  const float* W_qkv = (const float*)d_in[1];
  const float* b_qkv = (const float*)d_in[2];
  const float* W_out = (const float*)d_in[3];
  const float* b_out = (const float*)d_in[4];
  float* out = (float*)d_out;
  char* ws = (char*)d_ws;

  // ws layout (bytes)
  u16* xb    = (u16*)(ws);                               // 8 MB  [4096][1024]
  u16* WqkvT = (u16*)(ws + 8388608);                     // 6 MB  [3072][1024]
  u16* WoutT = (u16*)(ws + 8388608 + 6291456);           // 2 MB  [1024][1024]
  u16* Qb    = (u16*)(ws + 16777216);                    // 8 MB  [32][2048][64]
  u16* Kb    = (u16*)(ws + 16777216 + 8388608);          // 8 MB  [32][2048][64]
  u16* Vtb   = (u16*)(ws + 16777216 + 2 * 8388608);      // 8 MB  [32][64][2048]
  u16* Ob    = (u16*)(ws + 16777216 + 3 * 8388608);      // 8 MB  [4096][1024]

  cvt_kernel<<<4096, 256, 0, stream>>>(x, xb, BATCH * SEQ * DIM / 4);
  transpose_cvt_kernel<<<dim3(3 * DIM / 32, DIM / 32), dim3(32, 8), 0, stream>>>(
      W_qkv, WqkvT, DIM, 3 * DIM);
  transpose_cvt_kernel<<<dim3(DIM / 32, DIM / 32), dim3(32, 8), 0, stream>>>(
      W_out, WoutT, DIM, DIM);
  gemm_bt_kernel<0><<<dim3(3 * DIM / 128, BATCH * SEQ / 128), 256, 0, stream>>>(
      xb, WqkvT, b_qkv, nullptr, Qb, Kb, Vtb, BATCH * SEQ, 3 * DIM, DIM);
  attn_kernel<<<dim3(SEQ / 128, BATCH * NH), 256, 0, stream>>>(Qb, Kb, Vtb, Ob);
  gemm_bt_kernel<1><<<dim3(DIM / 128, BATCH * SEQ / 128), 256, 0, stream>>>(
      Ob, WoutT, b_out, out, nullptr, nullptr, nullptr, BATCH * SEQ, DIM, DIM);
}